// Round 9
// baseline (414.582 us; speedup 1.0000x reference)
//
#include <hip/hip_runtime.h>
#include <hip/hip_bf16.h>

#define HN 16
#define DM 1024
#define DK 64
#define BSZ 8
#define SEQL 1024

typedef __attribute__((ext_vector_type(8))) short bf16x8;
typedef __attribute__((ext_vector_type(4))) short short4v;
typedef __attribute__((ext_vector_type(4))) float f32x4;

__device__ __forceinline__ short f2bf(float f) {
    union { float f; unsigned u; } x; x.f = f;
    unsigned u = x.u + 0x7FFFu + ((x.u >> 16) & 1u);
    return (short)(u >> 16);
}

// async global->LDS, 16B per lane. LDS dest is wave-uniform base + lane*16.
__device__ __forceinline__ void async16(const void* g, void* ldsbase) {
    __builtin_amdgcn_global_load_lds(
        (const __attribute__((address_space(1))) unsigned int*)g,
        (__attribute__((address_space(3))) unsigned int*)ldsbase, 16, 0, 0);
}

// pack 4 f32 -> 4 bf16 (RNE) via v_cvt_pk_bf16_f32
__device__ __forceinline__ short4v pack4bf(float v0, float v1, float v2, float v3) {
    unsigned pk0, pk1;
    asm("v_cvt_pk_bf16_f32 %0, %1, %2" : "=v"(pk0) : "v"(v0), "v"(v1));
    asm("v_cvt_pk_bf16_f32 %0, %1, %2" : "=v"(pk1) : "v"(v2), "v"(v3));
    union { unsigned u[2]; short4v s4; } u_;
    u_.u[0] = pk0; u_.u[1] = pk1;
    return u_.s4;
}

__device__ __forceinline__ bf16x8 pack8bf(f32x4 lo, f32x4 hi) {
    union { short4v h[2]; bf16x8 v; } u_;
    u_.h[0] = pack4bf(lo.x, lo.y, lo.z, lo.w);
    u_.h[1] = pack4bf(hi.x, hi.y, hi.z, hi.w);
    return u_.v;
}

// ---------------------------------------------------------------------------
// Wt[n][k] = bf16(W[k][n]), 4 weight matrices in one launch (z selects)
// ---------------------------------------------------------------------------
__global__ __launch_bounds__(256) void transpose_cast4(const float* __restrict__ W0,
                                                       const float* __restrict__ W1,
                                                       const float* __restrict__ W2,
                                                       const float* __restrict__ W3,
                                                       short* __restrict__ T0,
                                                       short* __restrict__ T1,
                                                       short* __restrict__ T2,
                                                       short* __restrict__ T3) {
    __shared__ float tile[32][33];
    const int zi = blockIdx.z;
    const float* W = zi == 0 ? W0 : zi == 1 ? W1 : zi == 2 ? W2 : W3;
    short* Wt = zi == 0 ? T0 : zi == 1 ? T1 : zi == 2 ? T2 : T3;
    const int t = threadIdx.x;
    const int k0 = blockIdx.x * 32, n0 = blockIdx.y * 32;
    const int c = t & 31, r = t >> 5;
    #pragma unroll
    for (int p = 0; p < 4; ++p)
        tile[r + 8 * p][c] = W[(size_t)(k0 + r + 8 * p) * DM + n0 + c];
    __syncthreads();
    #pragma unroll
    for (int p = 0; p < 4; ++p)
        Wt[(size_t)(n0 + r + 8 * p) * DM + k0 + c] = f2bf(tile[c][r + 8 * p]);
}

// ---------------------------------------------------------------------------
// mask int32 -> u16 bit-tiles bt[z*1024+row][quad*16 + jblk] (1 = keep).
// ---------------------------------------------------------------------------
__global__ __launch_bounds__(256) void pack_mask(const int* __restrict__ mask,
                                                 unsigned short* __restrict__ bt) {
    size_t gi = (size_t)blockIdx.x * 256 + threadIdx.x;
    size_t word = gi >> 6;          // (z*1024 + row)*16 + jblk
    int l = threadIdx.x & 63;
    int jperm = ((l >> 2) & 3) * 16 + ((l >> 4) & 3) * 4 + (l & 3);
    size_t row = word >> 4;
    int jblk = (int)(word & 15);
    unsigned long long b = __ballot(mask[row * SEQL + jblk * 64 + jperm] != 0);
    if (l < 4)
        bt[row * 64 + l * 16 + jblk] = (unsigned short)(b >> (l * 16));
}

// ---------------------------------------------------------------------------
// Merged Q/K/V projection GEMM: grid (8, 8, 3*zdim); blockIdx.z>>zlog picks
// tensor (0=Q, 1=K, 2=V). A reg-staged: fp32 global -> regs (issued before
// MFMA, flies under it) -> cvt_pk bf16 -> ds_write into PADDED As[128][40]
// (pad makes fragment b128 reads 2-way = free). B DMA-staged (m97 pattern).
// 36KB LDS -> 4 blocks/CU. Spill-robust single __syncthreads per iter.
// which 0/1: C bf16 head-split [h][s][dk]; which 2: C bf16 [h][dk][s].
// ---------------------------------------------------------------------------
__global__ __launch_bounds__(256) void gemm_qkv(
    const float* __restrict__ Aq, const float* __restrict__ Ak,
    const float* __restrict__ Av,
    const short* __restrict__ Wqt, const short* __restrict__ Wkt,
    const short* __restrict__ Wvt,
    const float* __restrict__ bqp, const float* __restrict__ bkp,
    const float* __restrict__ bvp,
    short* __restrict__ Cq, short* __restrict__ Ck, short* __restrict__ Cv,
    int zlog) {
    __shared__ __attribute__((aligned(16))) short As[2][128][40];
    __shared__ __attribute__((aligned(16))) short Bs[2][128][32];
    const int t = threadIdx.x;
    const int lane = t & 63, wv = t >> 6;
    const int wm = (wv >> 1) * 64, wn = (wv & 1) * 64;
    const int quad = lane >> 4, l15 = lane & 15;
    const int tileM = blockIdx.x * 128, tileN = blockIdx.y * 128;
    const int which = blockIdx.z >> zlog;
    const int zz = blockIdx.z & ((1 << zlog) - 1);
    const size_t zoff = (size_t)zz * DM * SEQL;
    const float* A = (which == 0 ? Aq : which == 1 ? Ak : Av) + zoff;
    const short* Wt = which == 0 ? Wqt : which == 1 ? Wkt : Wvt;
    const float* bias = which == 0 ? bqp : which == 1 ? bkp : bvp;
    short* C = (which == 0 ? Cq : which == 1 ? Ck : Cv) + zoff;

    // A reg-staging: thread t -> row t>>1, fp32 col base (t&1)*16, 16 floats
    const int arow = t >> 1;
    const int acol = (t & 1) * 16;
    const float* asrc = A + (size_t)(tileM + arow) * DM + acol;
    // B DMA staging (2 calls of 64 rows): proven m97 pattern
    const int brow = t >> 2;
    const int bcol = (t & 3) * 8;
    const short* bsrc = Wt + (size_t)(tileN + brow) * DM + bcol;

    f32x4 acc[4][4];
    #pragma unroll
    for (int i = 0; i < 4; ++i)
        #pragma unroll
        for (int j = 0; j < 4; ++j) acc[i][j] = {0.f, 0.f, 0.f, 0.f};

    // prologue: stage tile 0 into buf 0
    {
        f32x4 r0 = *(const f32x4*)(asrc + 0);
        f32x4 r1 = *(const f32x4*)(asrc + 4);
        f32x4 r2 = *(const f32x4*)(asrc + 8);
        f32x4 r3 = *(const f32x4*)(asrc + 12);
        #pragma unroll
        for (int p = 0; p < 2; ++p)
            async16(bsrc + (size_t)(p * 64) * DM, &Bs[0][p * 64 + wv * 16][0]);
        *(bf16x8*)&As[0][arow][acol] = pack8bf(r0, r1);
        *(bf16x8*)&As[0][arow][acol + 8] = pack8bf(r2, r3);
    }
    __syncthreads();

    #pragma unroll 2
    for (int idx = 0; idx < DM / 32; ++idx) {
        const int cur = idx & 1;
        const int k0 = idx * 32;
        const bool more = (k0 + 32 < DM);
        f32x4 n0, n1, n2, n3;
        if (more) {
            // issue next A tile loads (fly under MFMA) + next B DMA
            n0 = *(const f32x4*)(asrc + k0 + 32);
            n1 = *(const f32x4*)(asrc + k0 + 36);
            n2 = *(const f32x4*)(asrc + k0 + 40);
            n3 = *(const f32x4*)(asrc + k0 + 44);
            #pragma unroll
            for (int p = 0; p < 2; ++p)
                async16(bsrc + (size_t)(p * 64) * DM + (k0 + 32),
                        &Bs[cur ^ 1][p * 64 + wv * 16][0]);
        }

        bf16x8 a[4], b[4];
        #pragma unroll
        for (int i = 0; i < 4; ++i)
            a[i] = *(const bf16x8*)&As[cur][wm + i * 16 + l15][quad * 8];
        #pragma unroll
        for (int j = 0; j < 4; ++j)
            b[j] = *(const bf16x8*)&Bs[cur][wn + j * 16 + l15][quad * 8];
        #pragma unroll
        for (int i = 0; i < 4; ++i)
            #pragma unroll
            for (int j = 0; j < 4; ++j)
                acc[i][j] = __builtin_amdgcn_mfma_f32_16x16x32_bf16(a[i], b[j], acc[i][j], 0, 0, 0);

        if (more) {
            // loads have had the whole MFMA phase to land; compiler inserts wait
            *(bf16x8*)&As[cur ^ 1][arow][acol] = pack8bf(n0, n1);
            *(bf16x8*)&As[cur ^ 1][arow][acol + 8] = pack8bf(n2, n3);
        }
        __syncthreads();  // B DMA drained, A writes visible, buf[cur] reads done
    }

    if (which == 2) {
        // V: C[h][dk][s], rr are consecutive s-rows at fixed col -> 8B store
        #pragma unroll
        for (int i = 0; i < 4; ++i)
            #pragma unroll
            for (int j = 0; j < 4; ++j) {
                int rowb = tileM + wm + i * 16 + quad * 4;
                int col = tileN + wn + j * 16 + l15;
                float bb = bias[col];
                short4v s4 = pack4bf(acc[i][j][0] + bb, acc[i][j][1] + bb,
                                     acc[i][j][2] + bb, acc[i][j][3] + bb);
                *(short4v*)(C + (size_t)col * SEQL + rowb) = s4;
            }
    } else {
        #pragma unroll
        for (int i = 0; i < 4; ++i)
            #pragma unroll
            for (int j = 0; j < 4; ++j)
                #pragma unroll
                for (int rr = 0; rr < 4; ++rr) {
                    int row = tileM + wm + i * 16 + quad * 4 + rr;
                    int col = tileN + wn + j * 16 + l15;
                    float v = acc[i][j][rr] + bias[col];
                    C[((size_t)(col >> 6) * SEQL + row) * DK + (col & 63)] = f2bf(v);
                }
    }
}

// ---------------------------------------------------------------------------
// Output projection GEMM (bf16 A = ctx, fp32 C). 2-phase single-barrier
// double-buffer (proven R6).
// ---------------------------------------------------------------------------
__global__ __launch_bounds__(256) void gemm_out(const short* __restrict__ A,
                                                const short* __restrict__ Wt,
                                                const float* __restrict__ bias,
                                                float* __restrict__ Cp) {
    __shared__ __attribute__((aligned(16))) short As[2][128][32];
    __shared__ __attribute__((aligned(16))) short Bs[2][128][32];
    const int t = threadIdx.x;
    const int lane = t & 63, wv = t >> 6;
    const int wm = (wv >> 1) * 64, wn = (wv & 1) * 64;
    const int quad = lane >> 4, l15 = lane & 15;
    const int tileM = blockIdx.x * 128, tileN = blockIdx.y * 128;
    const size_t zoff = (size_t)blockIdx.z * DM * SEQL;
    const short* Az = A + zoff;

    const int sr = wv * 16 + (lane >> 2);
    const int sc = (lane & 3) * 8;
    const short* asrc = Az + (size_t)(tileM + sr) * DM + sc;
    const short* bsrc = Wt + (size_t)(tileN + sr) * DM + sc;

    f32x4 acc[4][4];
    #pragma unroll
    for (int i = 0; i < 4; ++i)
        #pragma unroll
        for (int j = 0; j < 4; ++j) acc[i][j] = {0.f, 0.f, 0.f, 0.f};

    #pragma unroll
    for (int p = 0; p < 2; ++p) {
        async16(asrc + (size_t)p * 64 * DM, &As[0][p * 64 + wv * 16][0]);
        async16(bsrc + (size_t)p * 64 * DM, &Bs[0][p * 64 + wv * 16][0]);
    }
    __syncthreads();

    #pragma unroll 2
    for (int idx = 0; idx < DM / 32; ++idx) {
        const int cur = idx & 1;
        const int k0 = idx * 32;
        if (k0 + 32 < DM) {
            #pragma unroll
            for (int p = 0; p < 2; ++p) {
                async16(asrc + (size_t)p * 64 * DM + (k0 + 32),
                        &As[cur ^ 1][p * 64 + wv * 16][0]);
                async16(bsrc + (size_t)p * 64 * DM + (k0 + 32),
                        &Bs[cur ^ 1][p * 64 + wv * 16][0]);
            }
        }

        bf16x8 a[4], b[4];
        #pragma unroll
        for (int i = 0; i < 4; ++i) a[i] = *(const bf16x8*)&As[cur][wm + i * 16 + l15][quad * 8];
        #pragma unroll
        for (int j = 0; j < 4; ++j) b[j] = *(const bf16x8*)&Bs[cur][wn + j * 16 + l15][quad * 8];
        #pragma unroll
        for (int i = 0; i < 4; ++i)
            #pragma unroll
            for (int j = 0; j < 4; ++j)
                acc[i][j] = __builtin_amdgcn_mfma_f32_16x16x32_bf16(a[i], b[j], acc[i][j], 0, 0, 0);

        __syncthreads();
    }

    float* C = Cp + zoff;
    #pragma unroll
    for (int i = 0; i < 4; ++i)
        #pragma unroll
        for (int j = 0; j < 4; ++j)
            #pragma unroll
            for (int rr = 0; rr < 4; ++rr) {
                int row = tileM + wm + i * 16 + quad * 4 + rr;
                int col = tileN + wn + j * 16 + l15;
                C[(size_t)row * DM + col] = acc[i][j][rr] + bias[col];
            }
}

// ---------------------------------------------------------------------------
// MFMA attention, 2-phase double-buffered, spill-robust single-barrier loop
// (exact R6 kernel: proven 70us; setprio REVERTED -- m190: hurts lockstep).
// ---------------------------------------------------------------------------
template <bool USE_BITS>
__global__ __launch_bounds__(256) void attn_mfma(const short* __restrict__ Qw,
                                                 const short* __restrict__ Kw,
                                                 const short* __restrict__ Vt,
                                                 const void* __restrict__ maskp,
                                                 short* __restrict__ ctx) {
    __shared__ __attribute__((aligned(16))) short Kbuf[2][64 * 64];
    __shared__ __attribute__((aligned(16))) short Vbuf[2][64 * 64];  // [d][j]
    __shared__ __attribute__((aligned(16))) short Ps[4][16 * 64];    // per-wave [q][j]
    const int t = threadIdx.x;
    const int lane = t & 63, w = t >> 6;
    const int quad = lane >> 4, l15 = lane & 15;
    const int nwg = gridDim.x;            // 256*zdim, % 8 == 0
    const int cpx = nwg >> 3;
    const int vb = (blockIdx.x & 7) * cpx + (blockIdx.x >> 3);
    const int q0 = (vb & 15) * 64;
    const int h = (vb >> 4) & 15;
    const int z = vb >> 8;
    const size_t zoff = (size_t)z * DM * SEQL;
    const short* Qb = Qw + zoff + (size_t)h * SEQL * DK;
    const short* Kb = Kw + zoff + (size_t)h * SEQL * DK;
    const short* Vb = Vt + zoff + (size_t)h * DK * SEQL;
    const int qrow = q0 + w * 16 + l15;
    const int x = (l15 & 7) << 3;  // read-side swizzle (in shorts)

    bf16x8 qf0 = *(const bf16x8*)(Qb + (size_t)qrow * DK + quad * 8);
    bf16x8 qf1 = *(const bf16x8*)(Qb + (size_t)qrow * DK + 32 + quad * 8);

    unsigned long long mA = 0, mB = 0, mC = 0, mD = 0;
    if (USE_BITS) {
        const unsigned long long* bt64 = (const unsigned long long*)
            ((const unsigned short*)maskp + (size_t)z * SEQL * 64 +
             (size_t)qrow * 64 + quad * 16);
        mA = bt64[0]; mB = bt64[1]; mC = bt64[2]; mD = bt64[3];
    }

    const int r0 = t >> 3;                       // 0..31
    const int kc = ((t & 7) ^ (r0 & 7)) * 8;
    const short* ks0 = Kb + (size_t)r0 * DK + kc;
    const short* ks1 = ks0 + 32 * DK;
    const short* vs0 = Vb + (size_t)r0 * SEQL + kc;
    const short* vs1 = vs0 + 32 * SEQL;

    async16(ks0, &Kbuf[0][w * 512]);
    async16(ks1, &Kbuf[0][2048 + w * 512]);
    async16(vs0, &Vbuf[0][w * 512]);
    async16(vs1, &Vbuf[0][2048 + w * 512]);
    ks0 += 64 * DK; ks1 += 64 * DK; vs0 += 64; vs1 += 64;
    __syncthreads();

    f32x4 o[4];
    #pragma unroll
    for (int td = 0; td < 4; ++td) o[td] = {0.f, 0.f, 0.f, 0.f};
    float Lacc = 0.f;

    #pragma unroll 2
    for (int iter = 0; iter < 16; ++iter) {
        const int cur = iter & 1;
        if (iter < 15) {
            async16(ks0, &Kbuf[cur ^ 1][w * 512]);
            async16(ks1, &Kbuf[cur ^ 1][2048 + w * 512]);
            async16(vs0, &Vbuf[cur ^ 1][w * 512]);
            async16(vs1, &Vbuf[cur ^ 1][2048 + w * 512]);
            ks0 += 64 * DK; ks1 += 64 * DK; vs0 += 64; vs1 += 64;
        }

        const short* Kl = &Kbuf[cur][0];
        const short* Vl = &Vbuf[cur][0];
        unsigned mw16 = 0;
        if (USE_BITS) {
            unsigned long long t01 = (iter & 4) ? mB : mA;
            unsigned long long t23 = (iter & 4) ? mD : mC;
            unsigned long long tw = (iter & 8) ? t23 : t01;
            mw16 = (unsigned)(tw >> ((iter & 3) * 16)) & 0xFFFFu;
        }

        #pragma unroll
        for (int tn = 0; tn < 4; ++tn) {
            const int r = tn * 16 + l15;
            bf16x8 ak0 = *(const bf16x8*)&Kl[r * 64 + ((quad * 8) ^ x)];
            bf16x8 ak1 = *(const bf16x8*)&Kl[r * 64 + ((32 + quad * 8) ^ x)];
            f32x4 s = {0.f, 0.f, 0.f, 0.f};
            s = __builtin_amdgcn_mfma_f32_16x16x32_bf16(ak0, qf0, s, 0, 0, 0);
            s = __builtin_amdgcn_mfma_f32_16x16x32_bf16(ak1, qf1, s, 0, 0, 0);
            float pv[4];
            const unsigned nib = USE_BITS ? (mw16 >> (tn * 4)) & 0xFu : 0u;
            #pragma unroll
            for (int rr = 0; rr < 4; ++rr) {
                bool keep;
                if (USE_BITS) {
                    keep = (nib >> rr) & 1u;
                } else {
                    const int* mi = (const int*)maskp + (size_t)z * SEQL * SEQL;
                    keep = mi[(size_t)qrow * SEQL + iter * 64 + tn * 16 + quad * 4 + rr] != 0;
                }
                float e = __expf(s[rr] * 0.125f);
                pv[rr] = keep ? e : 0.0f;
                Lacc += pv[rr];
            }
            *(short4v*)&Ps[w][l15 * 64 + ((tn * 16 + quad * 4) ^ x)] =
                pack4bf(pv[0], pv[1], pv[2], pv[3]);
        }
        bf16x8 ap0 = *(const bf16x8*)&Ps[w][l15 * 64 + ((quad * 8) ^ x)];
        bf16x8 ap1 = *(const bf16x8*)&Ps[w][l15 * 64 + ((32 + quad * 8) ^ x)];
        #pragma unroll
        for (int td = 0; td < 4; ++td) {
            const int r = td * 16 + l15;
            bf16x8 bv0 = *(const bf16x8*)&Vl[r * 64 + ((quad * 8) ^ x)];
            bf16x8 bv1 = *(const bf16x8*)&Vl[r * 64 + ((32 + quad * 8) ^ x)];
            o[td] = __builtin_amdgcn_mfma_f32_16x16x32_bf16(ap0, bv0, o[td], 0, 0, 0);
            o[td] = __builtin_amdgcn_mfma_f32_16x16x32_bf16(ap1, bv1, o[td], 0, 0, 0);
        }

        __syncthreads();
    }

    Lacc += __shfl_xor(Lacc, 16);
    Lacc += __shfl_xor(Lacc, 32);
    float Linv = 1.0f / Lacc;
    float Linv4[4];
    #pragma unroll
    for (int rr = 0; rr < 4; ++rr)
        Linv4[rr] = __shfl(Linv, quad * 4 + rr);

    short* cb = ctx + zoff;
    #pragma unroll
    for (int td = 0; td < 4; ++td)
        #pragma unroll
        for (int rr = 0; rr < 4; ++rr) {
            int rq = q0 + w * 16 + quad * 4 + rr;
            int cd = h * 64 + td * 16 + l15;
            cb[(size_t)rq * DM + cd] = f2bf(o[td][rr] * Linv4[rr]);
        }
}

extern "C" void kernel_launch(void* const* d_in, const int* in_sizes, int n_in,
                              void* d_out, int out_size, void* d_ws, size_t ws_size,
                              hipStream_t stream) {
    const float* q  = (const float*)d_in[0];
    const float* k  = (const float*)d_in[1];
    const float* v  = (const float*)d_in[2];
    const int* mask = (const int*)d_in[3];
    const float* Wq = (const float*)d_in[4];
    const float* bq = (const float*)d_in[5];
    const float* Wk = (const float*)d_in[6];
    const float* bk = (const float*)d_in[7];
    const float* Wv = (const float*)d_in[8];
    const float* bv = (const float*)d_in[9];
    const float* Wo = (const float*)d_in[10];
    const float* bo = (const float*)d_in[11];
    float* out = (float*)d_out;

    const size_t MB = (size_t)1 << 20;
    const size_t MEL = (size_t)1024 * 1024;
    char* base = (char*)d_ws;

    short* Wqt = (short*)(base + 0 * 2 * MB);
    short* Wkt = (short*)(base + 1 * 2 * MB);
    short* Wvt = (short*)(base + 2 * 2 * MB);
    short* Wot = (short*)(base + 3 * 2 * MB);

    // tiers: weights 8MB [+ bits 1MB] + 4 bufs * z * 2MB
    int zdim;
    bool use_bits;
    if      (ws_size >= 74 * MB) { zdim = 8; use_bits = true; }
    else if (ws_size >= 42 * MB) { zdim = 4; use_bits = true; }
    else if (ws_size >= 26 * MB) { zdim = 2; use_bits = true; }
    else if (ws_size >= 18 * MB) { zdim = 1; use_bits = true; }
    else                         { zdim = 1; use_bits = false; }
    const int zlog = (zdim == 8) ? 3 : (zdim == 4) ? 2 : (zdim == 2) ? 1 : 0;

    unsigned short* bits = (unsigned short*)(base + 8 * MB);
    char* bufs = base + (use_bits ? 9 : 8) * MB;
    const size_t bufB = (size_t)zdim * 2 * MB;
    short* Qw  = (short*)(bufs);
    short* Kw  = (short*)(bufs + bufB);
    short* Vw  = (short*)(bufs + 2 * bufB);
    short* ctx = (short*)(bufs + 3 * bufB);

    transpose_cast4<<<dim3(32, 32, 4), 256, 0, stream>>>(Wq, Wk, Wv, Wo,
                                                         Wqt, Wkt, Wvt, Wot);
    if (use_bits)
        pack_mask<<<(BSZ * SEQL * SEQL) / 256, 256, 0, stream>>>(mask, bits);

    const int iters = BSZ / zdim;
    for (int it = 0; it < iters; ++it) {
        const size_t boff = (size_t)it * zdim * MEL;
        const float* qb = q + boff;
        const float* kb = k + boff;
        const float* vb = v + boff;
        float* ob = out + boff;
        const void* mb = use_bits
            ? (const void*)(bits + (size_t)it * zdim * SEQL * 64)
            : (const void*)(mask + (size_t)it * zdim * SEQL * SEQL);

        gemm_qkv<<<dim3(8, 8, 3 * zdim), 256, 0, stream>>>(
            qb, kb, vb, Wqt, Wkt, Wvt, bq, bk, bv, Qw, Kw, Vw, zlog);

        const int attnBlocks = 16 * 16 * zdim;  // 1D, XCD-swizzled in-kernel
        if (use_bits)
            attn_mfma<true><<<attnBlocks, 256, 0, stream>>>(Qw, Kw, Vw, mb, ctx);
        else
            attn_mfma<false><<<attnBlocks, 256, 0, stream>>>(Qw, Kw, Vw, mb, ctx);

        gemm_out<<<dim3(8, 8, zdim), 256, 0, stream>>>(ctx, Wot, bo, ob);
    }
}

// Round 12
// 375.536 us; speedup vs baseline: 1.1040x; 1.1040x over previous
//
#include <hip/hip_runtime.h>
#include <hip/hip_bf16.h>

#define HN 16
#define DM 1024
#define DK 64
#define BSZ 8
#define SEQL 1024

typedef __attribute__((ext_vector_type(8))) short bf16x8;
typedef __attribute__((ext_vector_type(4))) short short4v;
typedef __attribute__((ext_vector_type(4))) float f32x4;

__device__ __forceinline__ short f2bf(float f) {
    union { float f; unsigned u; } x; x.f = f;
    unsigned u = x.u + 0x7FFFu + ((x.u >> 16) & 1u);
    return (short)(u >> 16);
}

// async global->LDS, 16B per lane. LDS dest is wave-uniform base + lane*16.
__device__ __forceinline__ void async16(const void* g, void* ldsbase) {
    __builtin_amdgcn_global_load_lds(
        (const __attribute__((address_space(1))) unsigned int*)g,
        (__attribute__((address_space(3))) unsigned int*)ldsbase, 16, 0, 0);
}

// pack 4 f32 -> 4 bf16 (RNE) via v_cvt_pk_bf16_f32
__device__ __forceinline__ short4v pack4bf(float v0, float v1, float v2, float v3) {
    unsigned pk0, pk1;
    asm("v_cvt_pk_bf16_f32 %0, %1, %2" : "=v"(pk0) : "v"(v0), "v"(v1));
    asm("v_cvt_pk_bf16_f32 %0, %1, %2" : "=v"(pk1) : "v"(v2), "v"(v3));
    union { unsigned u[2]; short4v s4; } u_;
    u_.u[0] = pk0; u_.u[1] = pk1;
    return u_.s4;
}

// ---------------------------------------------------------------------------
// fp32 -> bf16 cast, 8 elems/thread
// ---------------------------------------------------------------------------
__global__ __launch_bounds__(256) void cast_bf16(const float* __restrict__ in,
                                                 short* __restrict__ out) {
    size_t i = (size_t)blockIdx.x * 256 + threadIdx.x;
    float4 a = ((const float4*)in)[2 * i];
    float4 b = ((const float4*)in)[2 * i + 1];
    bf16x8 r = {f2bf(a.x), f2bf(a.y), f2bf(a.z), f2bf(a.w),
                f2bf(b.x), f2bf(b.y), f2bf(b.z), f2bf(b.w)};
    ((bf16x8*)out)[i] = r;
}

// ---------------------------------------------------------------------------
// Wt[n][k] = bf16(W[k][n])
// ---------------------------------------------------------------------------
__global__ __launch_bounds__(256) void transpose_cast(const float* __restrict__ W,
                                                      short* __restrict__ Wt) {
    __shared__ float tile[32][33];
    const int t = threadIdx.x;
    const int k0 = blockIdx.x * 32, n0 = blockIdx.y * 32;
    const int c = t & 31, r = t >> 5;
    #pragma unroll
    for (int p = 0; p < 4; ++p)
        tile[r + 8 * p][c] = W[(size_t)(k0 + r + 8 * p) * DM + n0 + c];
    __syncthreads();
    #pragma unroll
    for (int p = 0; p < 4; ++p)
        Wt[(size_t)(n0 + r + 8 * p) * DM + k0 + c] = f2bf(tile[c][r + 8 * p]);
}

// ---------------------------------------------------------------------------
// mask int32 -> u16 bit-tiles bt[z*1024+row][quad*16 + jblk] (1 = keep).
// Bit (tn*4+rr) of bt[row][quad][jblk] = mask[row][jblk*64 + tn*16+quad*4+rr].
// ---------------------------------------------------------------------------
__global__ __launch_bounds__(256) void pack_mask(const int* __restrict__ mask,
                                                 unsigned short* __restrict__ bt) {
    size_t gi = (size_t)blockIdx.x * 256 + threadIdx.x;
    size_t word = gi >> 6;          // (z*1024 + row)*16 + jblk
    int l = threadIdx.x & 63;
    int jperm = ((l >> 2) & 3) * 16 + ((l >> 4) & 3) * 4 + (l & 3);
    size_t row = word >> 4;
    int jblk = (int)(word & 15);
    unsigned long long b = __ballot(mask[row * SEQL + jblk * 64 + jperm] != 0);
    if (l < 4)
        bt[row * 64 + l * 16 + jblk] = (unsigned short)(b >> (l * 16));
}

// ---------------------------------------------------------------------------
// MFMA GEMM, 64x128 tile (BM=64 halves per-block work, doubles grid to
// 1024 blocks = 4/CU resident -> latency hiding; this is the R6 template
// with only tile-size changed). BK=32, 4 waves, 2x4 frags/wave, 24KB LDS.
// 2-phase double-buffer, spill-robust single __syncthreads per iter.
// A is bf16 [s][k] (pre-cast), Wt is bf16 [n][k].
// MODE 0: C bf16 head-split [h][s][dk]   (Q/K projections)
// MODE 1: C fp32 row-major  [s][n]       (output projection)
// MODE 2: C bf16 V-transposed [h][dk][s] (V projection), packed 8B stores
// ---------------------------------------------------------------------------
template <int MODE>
__global__ __launch_bounds__(256) void gemm_mfma(const short* __restrict__ A,
                                                 const short* __restrict__ Wt,
                                                 const float* __restrict__ bias,
                                                 void* __restrict__ Cp) {
    __shared__ __attribute__((aligned(16))) short As[2][64][32];
    __shared__ __attribute__((aligned(16))) short Bs[2][128][32];
    const int t = threadIdx.x;
    const int lane = t & 63, wv = t >> 6;
    const int wm = (wv >> 1) * 32, wn = (wv & 1) * 64;
    const int quad = lane >> 4, l15 = lane & 15;
    const int tileM = blockIdx.x * 64, tileN = blockIdx.y * 128;
    const size_t zoff = (size_t)blockIdx.z * DM * SEQL;
    const short* Az = A + zoff;

    const int sr = wv * 16 + (lane >> 2);
    const int sc = (lane & 3) * 8;
    const short* asrc = Az + (size_t)(tileM + sr) * DM + sc;  // 64 rows, 1 call
    const short* bsrc = Wt + (size_t)(tileN + sr) * DM + sc;  // 128 rows, 2 calls

    f32x4 acc[2][4];
    #pragma unroll
    for (int i = 0; i < 2; ++i)
        #pragma unroll
        for (int j = 0; j < 4; ++j) acc[i][j] = {0.f, 0.f, 0.f, 0.f};

    // prologue: stage tile 0 into buf 0
    async16(asrc, &As[0][wv * 16][0]);
    #pragma unroll
    for (int p = 0; p < 2; ++p)
        async16(bsrc + (size_t)p * 64 * DM, &Bs[0][p * 64 + wv * 16][0]);
    __syncthreads();

    #pragma unroll 2
    for (int idx = 0; idx < DM / 32; ++idx) {
        const int cur = idx & 1;
        const int k0 = idx * 32;
        if (k0 + 32 < DM) {
            // stage NEXT tile into the other buffer; flies during MFMA below
            async16(asrc + (k0 + 32), &As[cur ^ 1][wv * 16][0]);
            #pragma unroll
            for (int p = 0; p < 2; ++p)
                async16(bsrc + (size_t)p * 64 * DM + (k0 + 32),
                        &Bs[cur ^ 1][p * 64 + wv * 16][0]);
        }

        bf16x8 a[2], b[4];
        #pragma unroll
        for (int i = 0; i < 2; ++i)
            a[i] = *(const bf16x8*)&As[cur][wm + i * 16 + l15][quad * 8];
        #pragma unroll
        for (int j = 0; j < 4; ++j)
            b[j] = *(const bf16x8*)&Bs[cur][wn + j * 16 + l15][quad * 8];
        #pragma unroll
        for (int i = 0; i < 2; ++i)
            #pragma unroll
            for (int j = 0; j < 4; ++j)
                acc[i][j] = __builtin_amdgcn_mfma_f32_16x16x32_bf16(a[i], b[j], acc[i][j], 0, 0, 0);

        // one barrier per iter: drains staging DMAs (next tile ready) AND
        // confirms all reads of buf[cur] done before it is restaged
        __syncthreads();
    }

    if (MODE == 2) {
        short* C = (short*)Cp + zoff;
        #pragma unroll
        for (int i = 0; i < 2; ++i)
            #pragma unroll
            for (int j = 0; j < 4; ++j) {
                int rowb = tileM + wm + i * 16 + quad * 4;
                int col = tileN + wn + j * 16 + l15;
                float b = bias[col];
                short4v s4 = pack4bf(acc[i][j][0] + b, acc[i][j][1] + b,
                                     acc[i][j][2] + b, acc[i][j][3] + b);
                *(short4v*)(C + (size_t)col * SEQL + rowb) = s4;  // [h][dk][s]
            }
    } else {
        #pragma unroll
        for (int i = 0; i < 2; ++i)
            #pragma unroll
            for (int j = 0; j < 4; ++j)
                #pragma unroll
                for (int rr = 0; rr < 4; ++rr) {
                    int row = tileM + wm + i * 16 + quad * 4 + rr;
                    int col = tileN + wn + j * 16 + l15;
                    float v = acc[i][j][rr] + bias[col];
                    if (MODE == 0) {
                        short* C = (short*)Cp + zoff;
                        C[((size_t)(col >> 6) * SEQL + row) * DK + (col & 63)] = f2bf(v);
                    } else {
                        float* C = (float*)Cp + zoff;
                        C[(size_t)row * DM + col] = v;
                    }
                }
    }
}

// ---------------------------------------------------------------------------
// MFMA attention, 2-phase double-buffered, spill-robust single-barrier loop
// (exact R6 kernel, proven 70us).
// ---------------------------------------------------------------------------
template <bool USE_BITS>
__global__ __launch_bounds__(256) void attn_mfma(const short* __restrict__ Qw,
                                                 const short* __restrict__ Kw,
                                                 const short* __restrict__ Vt,
                                                 const void* __restrict__ maskp,
                                                 short* __restrict__ ctx) {
    __shared__ __attribute__((aligned(16))) short Kbuf[2][64 * 64];
    __shared__ __attribute__((aligned(16))) short Vbuf[2][64 * 64];  // [d][j]
    __shared__ __attribute__((aligned(16))) short Ps[4][16 * 64];    // per-wave [q][j]
    const int t = threadIdx.x;
    const int lane = t & 63, w = t >> 6;
    const int quad = lane >> 4, l15 = lane & 15;
    const int nwg = gridDim.x;            // 256*zdim, % 8 == 0
    const int cpx = nwg >> 3;
    const int vb = (blockIdx.x & 7) * cpx + (blockIdx.x >> 3);
    const int q0 = (vb & 15) * 64;
    const int h = (vb >> 4) & 15;
    const int z = vb >> 8;
    const size_t zoff = (size_t)z * DM * SEQL;
    const short* Qb = Qw + zoff + (size_t)h * SEQL * DK;
    const short* Kb = Kw + zoff + (size_t)h * SEQL * DK;
    const short* Vb = Vt + zoff + (size_t)h * DK * SEQL;
    const int qrow = q0 + w * 16 + l15;
    const int x = (l15 & 7) << 3;  // read-side swizzle (in shorts)

    bf16x8 qf0 = *(const bf16x8*)(Qb + (size_t)qrow * DK + quad * 8);
    bf16x8 qf1 = *(const bf16x8*)(Qb + (size_t)qrow * DK + 32 + quad * 8);

    unsigned long long mA = 0, mB = 0, mC = 0, mD = 0;
    if (USE_BITS) {
        const unsigned long long* bt64 = (const unsigned long long*)
            ((const unsigned short*)maskp + (size_t)z * SEQL * 64 +
             (size_t)qrow * 64 + quad * 16);
        mA = bt64[0]; mB = bt64[1]; mC = bt64[2]; mD = bt64[3];
    }

    const int r0 = t >> 3;                       // 0..31
    const int kc = ((t & 7) ^ (r0 & 7)) * 8;
    const short* ks0 = Kb + (size_t)r0 * DK + kc;
    const short* ks1 = ks0 + 32 * DK;
    const short* vs0 = Vb + (size_t)r0 * SEQL + kc;
    const short* vs1 = vs0 + 32 * SEQL;

    async16(ks0, &Kbuf[0][w * 512]);
    async16(ks1, &Kbuf[0][2048 + w * 512]);
    async16(vs0, &Vbuf[0][w * 512]);
    async16(vs1, &Vbuf[0][2048 + w * 512]);
    ks0 += 64 * DK; ks1 += 64 * DK; vs0 += 64; vs1 += 64;
    __syncthreads();

    f32x4 o[4];
    #pragma unroll
    for (int td = 0; td < 4; ++td) o[td] = {0.f, 0.f, 0.f, 0.f};
    float Lacc = 0.f;

    #pragma unroll 2
    for (int iter = 0; iter < 16; ++iter) {
        const int cur = iter & 1;
        if (iter < 15) {
            async16(ks0, &Kbuf[cur ^ 1][w * 512]);
            async16(ks1, &Kbuf[cur ^ 1][2048 + w * 512]);
            async16(vs0, &Vbuf[cur ^ 1][w * 512]);
            async16(vs1, &Vbuf[cur ^ 1][2048 + w * 512]);
            ks0 += 64 * DK; ks1 += 64 * DK; vs0 += 64; vs1 += 64;
        }

        const short* Kl = &Kbuf[cur][0];
        const short* Vl = &Vbuf[cur][0];
        unsigned mw16 = 0;
        if (USE_BITS) {
            unsigned long long t01 = (iter & 4) ? mB : mA;
            unsigned long long t23 = (iter & 4) ? mD : mC;
            unsigned long long tw = (iter & 8) ? t23 : t01;
            mw16 = (unsigned)(tw >> ((iter & 3) * 16)) & 0xFFFFu;
        }

        #pragma unroll
        for (int tn = 0; tn < 4; ++tn) {
            const int r = tn * 16 + l15;
            bf16x8 ak0 = *(const bf16x8*)&Kl[r * 64 + ((quad * 8) ^ x)];
            bf16x8 ak1 = *(const bf16x8*)&Kl[r * 64 + ((32 + quad * 8) ^ x)];
            f32x4 s = {0.f, 0.f, 0.f, 0.f};
            s = __builtin_amdgcn_mfma_f32_16x16x32_bf16(ak0, qf0, s, 0, 0, 0);
            s = __builtin_amdgcn_mfma_f32_16x16x32_bf16(ak1, qf1, s, 0, 0, 0);
            float pv[4];
            const unsigned nib = USE_BITS ? (mw16 >> (tn * 4)) & 0xFu : 0u;
            #pragma unroll
            for (int rr = 0; rr < 4; ++rr) {
                bool keep;
                if (USE_BITS) {
                    keep = (nib >> rr) & 1u;
                } else {
                    const int* mi = (const int*)maskp + (size_t)z * SEQL * SEQL;
                    keep = mi[(size_t)qrow * SEQL + iter * 64 + tn * 16 + quad * 4 + rr] != 0;
                }
                float e = __expf(s[rr] * 0.125f);
                pv[rr] = keep ? e : 0.0f;
                Lacc += pv[rr];
            }
            *(short4v*)&Ps[w][l15 * 64 + ((tn * 16 + quad * 4) ^ x)] =
                pack4bf(pv[0], pv[1], pv[2], pv[3]);
        }
        bf16x8 ap0 = *(const bf16x8*)&Ps[w][l15 * 64 + ((quad * 8) ^ x)];
        bf16x8 ap1 = *(const bf16x8*)&Ps[w][l15 * 64 + ((32 + quad * 8) ^ x)];
        #pragma unroll
        for (int td = 0; td < 4; ++td) {
            const int r = td * 16 + l15;
            bf16x8 bv0 = *(const bf16x8*)&Vl[r * 64 + ((quad * 8) ^ x)];
            bf16x8 bv1 = *(const bf16x8*)&Vl[r * 64 + ((32 + quad * 8) ^ x)];
            o[td] = __builtin_amdgcn_mfma_f32_16x16x32_bf16(ap0, bv0, o[td], 0, 0, 0);
            o[td] = __builtin_amdgcn_mfma_f32_16x16x32_bf16(ap1, bv1, o[td], 0, 0, 0);
        }

        __syncthreads();
    }

    Lacc += __shfl_xor(Lacc, 16);
    Lacc += __shfl_xor(Lacc, 32);
    float Linv = 1.0f / Lacc;
    float Linv4[4];
    #pragma unroll
    for (int rr = 0; rr < 4; ++rr)
        Linv4[rr] = __shfl(Linv, quad * 4 + rr);

    short* cb = ctx + zoff;
    #pragma unroll
    for (int td = 0; td < 4; ++td)
        #pragma unroll
        for (int rr = 0; rr < 4; ++rr) {
            int rq = q0 + w * 16 + quad * 4 + rr;
            int cd = h * 64 + td * 16 + l15;
            cb[(size_t)rq * DM + cd] = f2bf(o[td][rr] * Linv4[rr]);
        }
}

extern "C" void kernel_launch(void* const* d_in, const int* in_sizes, int n_in,
                              void* d_out, int out_size, void* d_ws, size_t ws_size,
                              hipStream_t stream) {
    const float* q  = (const float*)d_in[0];
    const float* k  = (const float*)d_in[1];
    const float* v  = (const float*)d_in[2];
    const int* mask = (const int*)d_in[3];
    const float* Wq = (const float*)d_in[4];
    const float* bq = (const float*)d_in[5];
    const float* Wk = (const float*)d_in[6];
    const float* bk = (const float*)d_in[7];
    const float* Wv = (const float*)d_in[8];
    const float* bv = (const float*)d_in[9];
    const float* Wo = (const float*)d_in[10];
    const float* bo = (const float*)d_in[11];
    float* out = (float*)d_out;

    const size_t MB = (size_t)1 << 20;
    const size_t MEL = (size_t)1024 * 1024;
    char* base = (char*)d_ws;

    short* Wqt = (short*)(base + 0 * 2 * MB);
    short* Wkt = (short*)(base + 1 * 2 * MB);
    short* Wvt = (short*)(base + 2 * 2 * MB);
    short* Wot = (short*)(base + 3 * 2 * MB);

    // tiers: weights 8MB [+ bits 1MB] + 4 bufs * z * 2MB
    int zdim;
    bool use_bits;
    if      (ws_size >= 74 * MB) { zdim = 8; use_bits = true; }
    else if (ws_size >= 42 * MB) { zdim = 4; use_bits = true; }
    else if (ws_size >= 26 * MB) { zdim = 2; use_bits = true; }
    else if (ws_size >= 18 * MB) { zdim = 1; use_bits = true; }
    else                         { zdim = 1; use_bits = false; }

    unsigned short* bits = (unsigned short*)(base + 8 * MB);
    char* bufs = base + (use_bits ? 9 : 8) * MB;
    const size_t bufB = (size_t)zdim * 2 * MB;
    short* Qw  = (short*)(bufs);
    short* Kw  = (short*)(bufs + bufB);
    short* Vw  = (short*)(bufs + 2 * bufB);
    short* ctx = (short*)(bufs + 3 * bufB);

    transpose_cast<<<dim3(32, 32), 256, 0, stream>>>(Wq, Wqt);
    transpose_cast<<<dim3(32, 32), 256, 0, stream>>>(Wk, Wkt);
    transpose_cast<<<dim3(32, 32), 256, 0, stream>>>(Wv, Wvt);
    transpose_cast<<<dim3(32, 32), 256, 0, stream>>>(Wo, Wot);
    if (use_bits)
        pack_mask<<<(BSZ * SEQL * SEQL) / 256, 256, 0, stream>>>(mask, bits);

    const int iters = BSZ / zdim;
    for (int it = 0; it < iters; ++it) {
        const size_t boff = (size_t)it * zdim * MEL;
        const float* qb = q + boff;
        const float* kb = k + boff;
        const float* vb = v + boff;
        float* ob = out + boff;
        const void* mb = use_bits
            ? (const void*)(bits + (size_t)it * zdim * SEQL * 64)
            : (const void*)(mask + (size_t)it * zdim * SEQL * SEQL);

        const int castGrid = zdim * 512;  // zdim*1M elems / 8 per thread / 256
        // ctx is dead until attn writes it: reuse as bf16 A-scratch.
        cast_bf16<<<castGrid, 256, 0, stream>>>(qb, ctx);
        gemm_mfma<0><<<dim3(16, 8, zdim), 256, 0, stream>>>(ctx, Wqt, bq, Qw);
        cast_bf16<<<castGrid, 256, 0, stream>>>(kb, ctx);
        gemm_mfma<0><<<dim3(16, 8, zdim), 256, 0, stream>>>(ctx, Wkt, bk, Kw);
        cast_bf16<<<castGrid, 256, 0, stream>>>(vb, ctx);
        gemm_mfma<2><<<dim3(16, 8, zdim), 256, 0, stream>>>(ctx, Wvt, bv, Vw);

        const int attnBlocks = 16 * 16 * zdim;  // 1D, XCD-swizzled in-kernel
        if (use_bits)
            attn_mfma<true><<<attnBlocks, 256, 0, stream>>>(Qw, Kw, Vw, mb, ctx);
        else
            attn_mfma<false><<<attnBlocks, 256, 0, stream>>>(Qw, Kw, Vw, mb, ctx);

        gemm_mfma<1><<<dim3(16, 8, zdim), 256, 0, stream>>>(ctx, Wot, bo, ob);
    }
}

// Round 13
// 361.287 us; speedup vs baseline: 1.1475x; 1.0394x over previous
//
#include <hip/hip_runtime.h>
#include <hip/hip_bf16.h>

#define HN 16
#define DM 1024
#define DK 64
#define BSZ 8
#define SEQL 1024

typedef __attribute__((ext_vector_type(8))) short bf16x8;
typedef __attribute__((ext_vector_type(4))) short short4v;
typedef __attribute__((ext_vector_type(4))) float f32x4;

__device__ __forceinline__ short f2bf(float f) {
    union { float f; unsigned u; } x; x.f = f;
    unsigned u = x.u + 0x7FFFu + ((x.u >> 16) & 1u);
    return (short)(u >> 16);
}

// async global->LDS, 16B per lane. LDS dest is wave-uniform base + lane*16.
__device__ __forceinline__ void async16(const void* g, void* ldsbase) {
    __builtin_amdgcn_global_load_lds(
        (const __attribute__((address_space(1))) unsigned int*)g,
        (__attribute__((address_space(3))) unsigned int*)ldsbase, 16, 0, 0);
}

// pack 4 f32 -> 4 bf16 (RNE) via v_cvt_pk_bf16_f32
__device__ __forceinline__ short4v pack4bf(float v0, float v1, float v2, float v3) {
    unsigned pk0, pk1;
    asm("v_cvt_pk_bf16_f32 %0, %1, %2" : "=v"(pk0) : "v"(v0), "v"(v1));
    asm("v_cvt_pk_bf16_f32 %0, %1, %2" : "=v"(pk1) : "v"(v2), "v"(v3));
    union { unsigned u[2]; short4v s4; } u_;
    u_.u[0] = pk0; u_.u[1] = pk1;
    return u_.s4;
}

// ---------------------------------------------------------------------------
// fp32 -> bf16 cast, 8 elems/thread
// ---------------------------------------------------------------------------
__global__ __launch_bounds__(256) void cast_bf16(const float* __restrict__ in,
                                                 short* __restrict__ out) {
    size_t i = (size_t)blockIdx.x * 256 + threadIdx.x;
    float4 a = ((const float4*)in)[2 * i];
    float4 b = ((const float4*)in)[2 * i + 1];
    bf16x8 r = {f2bf(a.x), f2bf(a.y), f2bf(a.z), f2bf(a.w),
                f2bf(b.x), f2bf(b.y), f2bf(b.z), f2bf(b.w)};
    ((bf16x8*)out)[i] = r;
}

// ---------------------------------------------------------------------------
// Wt[n][k] = bf16(W[k][n])
// ---------------------------------------------------------------------------
__global__ __launch_bounds__(256) void transpose_cast(const float* __restrict__ W,
                                                      short* __restrict__ Wt) {
    __shared__ float tile[32][33];
    const int t = threadIdx.x;
    const int k0 = blockIdx.x * 32, n0 = blockIdx.y * 32;
    const int c = t & 31, r = t >> 5;
    #pragma unroll
    for (int p = 0; p < 4; ++p)
        tile[r + 8 * p][c] = W[(size_t)(k0 + r + 8 * p) * DM + n0 + c];
    __syncthreads();
    #pragma unroll
    for (int p = 0; p < 4; ++p)
        Wt[(size_t)(n0 + r + 8 * p) * DM + k0 + c] = f2bf(tile[c][r + 8 * p]);
}

// ---------------------------------------------------------------------------
// mask int32 -> u16 bit-tiles bt[z*1024+row][quad*16 + jblk] (1 = keep).
// Bit (tn*4+rr) of bt[row][quad][jblk] = mask[row][jblk*64 + tn*16+quad*4+rr].
// ---------------------------------------------------------------------------
__global__ __launch_bounds__(256) void pack_mask(const int* __restrict__ mask,
                                                 unsigned short* __restrict__ bt) {
    size_t gi = (size_t)blockIdx.x * 256 + threadIdx.x;
    size_t word = gi >> 6;          // (z*1024 + row)*16 + jblk
    int l = threadIdx.x & 63;
    int jperm = ((l >> 2) & 3) * 16 + ((l >> 4) & 3) * 4 + (l & 3);
    size_t row = word >> 4;
    int jblk = (int)(word & 15);
    unsigned long long b = __ballot(mask[row * SEQL + jblk * 64 + jperm] != 0);
    if (l < 4)
        bt[row * 64 + l * 16 + jblk] = (unsigned short)(b >> (l * 16));
}

// ---------------------------------------------------------------------------
// MFMA GEMM, 128x128 tile, BK=64: halves the sync-event count (16 iters
// instead of 32) -- per-iter barrier/DMA-drain overhead was the binder
// (4 variants at BK=32 all ~66us). 64-col rows = 128B stride would be a
// 16-way bank conflict, so K/V-style XOR swizzle (pre-swizzled global
// source + ^x read), the exact pattern proven in attn since R6.
// 4 waves, 4x4 frags, 32 MFMA/iter/wave, 64KB LDS, grid (8,8,z) = 2/CU.
// 2-phase double-buffer, spill-robust single __syncthreads per iter.
// A is bf16 [s][k] (pre-cast), Wt is bf16 [n][k].
// MODE 0: C bf16 head-split [h][s][dk]   (Q/K projections)
// MODE 1: C fp32 row-major  [s][n]       (output projection)
// MODE 2: C bf16 V-transposed [h][dk][s] (V projection), packed 8B stores
// ---------------------------------------------------------------------------
template <int MODE>
__global__ __launch_bounds__(256) void gemm_mfma(const short* __restrict__ A,
                                                 const short* __restrict__ Wt,
                                                 const float* __restrict__ bias,
                                                 void* __restrict__ Cp) {
    __shared__ __attribute__((aligned(16))) short As[2][128][64];
    __shared__ __attribute__((aligned(16))) short Bs[2][128][64];
    const int t = threadIdx.x;
    const int lane = t & 63, wv = t >> 6;
    const int wm = (wv >> 1) * 64, wn = (wv & 1) * 64;
    const int quad = lane >> 4, l15 = lane & 15;
    const int tileM = blockIdx.x * 128, tileN = blockIdx.y * 128;
    const size_t zoff = (size_t)blockIdx.z * DM * SEQL;
    const short* Az = A + zoff;
    const int x = (l15 & 7) << 3;  // read-side swizzle (in shorts)

    // staging: call p covers rows p*32 + (t>>3); col ((t&7)^(row&7))*8
    // (row&7 == (t>>3)&7 since p*32 === 0 mod 8)
    const int r0 = t >> 3;                       // 0..31
    const int kc = ((t & 7) ^ (r0 & 7)) * 8;
    const short* asrc = Az + (size_t)(tileM + r0) * DM + kc;
    const short* bsrc = Wt + (size_t)(tileN + r0) * DM + kc;

    f32x4 acc[4][4];
    #pragma unroll
    for (int i = 0; i < 4; ++i)
        #pragma unroll
        for (int j = 0; j < 4; ++j) acc[i][j] = {0.f, 0.f, 0.f, 0.f};

    // prologue: stage tile 0 into buf 0 (8 calls of 32 rows each)
    #pragma unroll
    for (int p = 0; p < 4; ++p) {
        async16(asrc + (size_t)(p * 32) * DM, &As[0][p * 32 + wv * 8][0]);
        async16(bsrc + (size_t)(p * 32) * DM, &Bs[0][p * 32 + wv * 8][0]);
    }
    __syncthreads();

    #pragma unroll 2
    for (int idx = 0; idx < DM / 64; ++idx) {   // 16 iters
        const int cur = idx & 1;
        const int k0 = idx * 64;
        if (k0 + 64 < DM) {
            // stage NEXT tile into the other buffer; flies during MFMA below
            #pragma unroll
            for (int p = 0; p < 4; ++p) {
                async16(asrc + (size_t)(p * 32) * DM + (k0 + 64),
                        &As[cur ^ 1][p * 32 + wv * 8][0]);
                async16(bsrc + (size_t)(p * 32) * DM + (k0 + 64),
                        &Bs[cur ^ 1][p * 32 + wv * 8][0]);
            }
        }

        #pragma unroll
        for (int ks = 0; ks < 2; ++ks) {
            const int off = (ks * 32 + quad * 8) ^ x;
            bf16x8 a[4], b[4];
            #pragma unroll
            for (int i = 0; i < 4; ++i)
                a[i] = *(const bf16x8*)&As[cur][wm + i * 16 + l15][off];
            #pragma unroll
            for (int j = 0; j < 4; ++j)
                b[j] = *(const bf16x8*)&Bs[cur][wn + j * 16 + l15][off];
            #pragma unroll
            for (int i = 0; i < 4; ++i)
                #pragma unroll
                for (int j = 0; j < 4; ++j)
                    acc[i][j] = __builtin_amdgcn_mfma_f32_16x16x32_bf16(a[i], b[j], acc[i][j], 0, 0, 0);
        }

        // one barrier per iter: drains staging DMAs (next tile ready) AND
        // confirms all reads of buf[cur] done before it is restaged
        __syncthreads();
    }

    if (MODE == 2) {
        short* C = (short*)Cp + zoff;
        #pragma unroll
        for (int i = 0; i < 4; ++i)
            #pragma unroll
            for (int j = 0; j < 4; ++j) {
                int rowb = tileM + wm + i * 16 + quad * 4;
                int col = tileN + wn + j * 16 + l15;
                float b = bias[col];
                short4v s4 = pack4bf(acc[i][j][0] + b, acc[i][j][1] + b,
                                     acc[i][j][2] + b, acc[i][j][3] + b);
                *(short4v*)(C + (size_t)col * SEQL + rowb) = s4;  // [h][dk][s]
            }
    } else {
        #pragma unroll
        for (int i = 0; i < 4; ++i)
            #pragma unroll
            for (int j = 0; j < 4; ++j)
                #pragma unroll
                for (int rr = 0; rr < 4; ++rr) {
                    int row = tileM + wm + i * 16 + quad * 4 + rr;
                    int col = tileN + wn + j * 16 + l15;
                    float v = acc[i][j][rr] + bias[col];
                    if (MODE == 0) {
                        short* C = (short*)Cp + zoff;
                        C[((size_t)(col >> 6) * SEQL + row) * DK + (col & 63)] = f2bf(v);
                    } else {
                        float* C = (float*)Cp + zoff;
                        C[(size_t)row * DM + col] = v;
                    }
                }
    }
}

// ---------------------------------------------------------------------------
// MFMA attention, 2-phase double-buffered, spill-robust single-barrier loop
// (exact R6 kernel, proven 70us across three runs).
// ---------------------------------------------------------------------------
template <bool USE_BITS>
__global__ __launch_bounds__(256) void attn_mfma(const short* __restrict__ Qw,
                                                 const short* __restrict__ Kw,
                                                 const short* __restrict__ Vt,
                                                 const void* __restrict__ maskp,
                                                 short* __restrict__ ctx) {
    __shared__ __attribute__((aligned(16))) short Kbuf[2][64 * 64];
    __shared__ __attribute__((aligned(16))) short Vbuf[2][64 * 64];  // [d][j]
    __shared__ __attribute__((aligned(16))) short Ps[4][16 * 64];    // per-wave [q][j]
    const int t = threadIdx.x;
    const int lane = t & 63, w = t >> 6;
    const int quad = lane >> 4, l15 = lane & 15;
    const int nwg = gridDim.x;            // 256*zdim, % 8 == 0
    const int cpx = nwg >> 3;
    const int vb = (blockIdx.x & 7) * cpx + (blockIdx.x >> 3);
    const int q0 = (vb & 15) * 64;
    const int h = (vb >> 4) & 15;
    const int z = vb >> 8;
    const size_t zoff = (size_t)z * DM * SEQL;
    const short* Qb = Qw + zoff + (size_t)h * SEQL * DK;
    const short* Kb = Kw + zoff + (size_t)h * SEQL * DK;
    const short* Vb = Vt + zoff + (size_t)h * DK * SEQL;
    const int qrow = q0 + w * 16 + l15;
    const int x = (l15 & 7) << 3;  // read-side swizzle (in shorts)

    bf16x8 qf0 = *(const bf16x8*)(Qb + (size_t)qrow * DK + quad * 8);
    bf16x8 qf1 = *(const bf16x8*)(Qb + (size_t)qrow * DK + 32 + quad * 8);

    unsigned long long mA = 0, mB = 0, mC = 0, mD = 0;
    if (USE_BITS) {
        const unsigned long long* bt64 = (const unsigned long long*)
            ((const unsigned short*)maskp + (size_t)z * SEQL * 64 +
             (size_t)qrow * 64 + quad * 16);
        mA = bt64[0]; mB = bt64[1]; mC = bt64[2]; mD = bt64[3];
    }

    const int r0 = t >> 3;                       // 0..31
    const int kc = ((t & 7) ^ (r0 & 7)) * 8;
    const short* ks0 = Kb + (size_t)r0 * DK + kc;
    const short* ks1 = ks0 + 32 * DK;
    const short* vs0 = Vb + (size_t)r0 * SEQL + kc;
    const short* vs1 = vs0 + 32 * SEQL;

    async16(ks0, &Kbuf[0][w * 512]);
    async16(ks1, &Kbuf[0][2048 + w * 512]);
    async16(vs0, &Vbuf[0][w * 512]);
    async16(vs1, &Vbuf[0][2048 + w * 512]);
    ks0 += 64 * DK; ks1 += 64 * DK; vs0 += 64; vs1 += 64;
    __syncthreads();

    f32x4 o[4];
    #pragma unroll
    for (int td = 0; td < 4; ++td) o[td] = {0.f, 0.f, 0.f, 0.f};
    float Lacc = 0.f;

    #pragma unroll 2
    for (int iter = 0; iter < 16; ++iter) {
        const int cur = iter & 1;
        if (iter < 15) {
            async16(ks0, &Kbuf[cur ^ 1][w * 512]);
            async16(ks1, &Kbuf[cur ^ 1][2048 + w * 512]);
            async16(vs0, &Vbuf[cur ^ 1][w * 512]);
            async16(vs1, &Vbuf[cur ^ 1][2048 + w * 512]);
            ks0 += 64 * DK; ks1 += 64 * DK; vs0 += 64; vs1 += 64;
        }

        const short* Kl = &Kbuf[cur][0];
        const short* Vl = &Vbuf[cur][0];
        unsigned mw16 = 0;
        if (USE_BITS) {
            unsigned long long t01 = (iter & 4) ? mB : mA;
            unsigned long long t23 = (iter & 4) ? mD : mC;
            unsigned long long tw = (iter & 8) ? t23 : t01;
            mw16 = (unsigned)(tw >> ((iter & 3) * 16)) & 0xFFFFu;
        }

        #pragma unroll
        for (int tn = 0; tn < 4; ++tn) {
            const int r = tn * 16 + l15;
            bf16x8 ak0 = *(const bf16x8*)&Kl[r * 64 + ((quad * 8) ^ x)];
            bf16x8 ak1 = *(const bf16x8*)&Kl[r * 64 + ((32 + quad * 8) ^ x)];
            f32x4 s = {0.f, 0.f, 0.f, 0.f};
            s = __builtin_amdgcn_mfma_f32_16x16x32_bf16(ak0, qf0, s, 0, 0, 0);
            s = __builtin_amdgcn_mfma_f32_16x16x32_bf16(ak1, qf1, s, 0, 0, 0);
            float pv[4];
            const unsigned nib = USE_BITS ? (mw16 >> (tn * 4)) & 0xFu : 0u;
            #pragma unroll
            for (int rr = 0; rr < 4; ++rr) {
                bool keep;
                if (USE_BITS) {
                    keep = (nib >> rr) & 1u;
                } else {
                    const int* mi = (const int*)maskp + (size_t)z * SEQL * SEQL;
                    keep = mi[(size_t)qrow * SEQL + iter * 64 + tn * 16 + quad * 4 + rr] != 0;
                }
                float e = __expf(s[rr] * 0.125f);
                pv[rr] = keep ? e : 0.0f;
                Lacc += pv[rr];
            }
            *(short4v*)&Ps[w][l15 * 64 + ((tn * 16 + quad * 4) ^ x)] =
                pack4bf(pv[0], pv[1], pv[2], pv[3]);
        }
        bf16x8 ap0 = *(const bf16x8*)&Ps[w][l15 * 64 + ((quad * 8) ^ x)];
        bf16x8 ap1 = *(const bf16x8*)&Ps[w][l15 * 64 + ((32 + quad * 8) ^ x)];
        #pragma unroll
        for (int td = 0; td < 4; ++td) {
            const int r = td * 16 + l15;
            bf16x8 bv0 = *(const bf16x8*)&Vl[r * 64 + ((quad * 8) ^ x)];
            bf16x8 bv1 = *(const bf16x8*)&Vl[r * 64 + ((32 + quad * 8) ^ x)];
            o[td] = __builtin_amdgcn_mfma_f32_16x16x32_bf16(ap0, bv0, o[td], 0, 0, 0);
            o[td] = __builtin_amdgcn_mfma_f32_16x16x32_bf16(ap1, bv1, o[td], 0, 0, 0);
        }

        __syncthreads();
    }

    Lacc += __shfl_xor(Lacc, 16);
    Lacc += __shfl_xor(Lacc, 32);
    float Linv = 1.0f / Lacc;
    float Linv4[4];
    #pragma unroll
    for (int rr = 0; rr < 4; ++rr)
        Linv4[rr] = __shfl(Linv, quad * 4 + rr);

    short* cb = ctx + zoff;
    #pragma unroll
    for (int td = 0; td < 4; ++td)
        #pragma unroll
        for (int rr = 0; rr < 4; ++rr) {
            int rq = q0 + w * 16 + quad * 4 + rr;
            int cd = h * 64 + td * 16 + l15;
            cb[(size_t)rq * DM + cd] = f2bf(o[td][rr] * Linv4[rr]);
        }
}

extern "C" void kernel_launch(void* const* d_in, const int* in_sizes, int n_in,
                              void* d_out, int out_size, void* d_ws, size_t ws_size,
                              hipStream_t stream) {
    const float* q  = (const float*)d_in[0];
    const float* k  = (const float*)d_in[1];
    const float* v  = (const float*)d_in[2];
    const int* mask = (const int*)d_in[3];
    const float* Wq = (const float*)d_in[4];
    const float* bq = (const float*)d_in[5];
    const float* Wk = (const float*)d_in[6];
    const float* bk = (const float*)d_in[7];
    const float* Wv = (const float*)d_in[8];
    const float* bv = (const float*)d_in[9];
    const float* Wo = (const float*)d_in[10];
    const float* bo = (const float*)d_in[11];
    float* out = (float*)d_out;

    const size_t MB = (size_t)1 << 20;
    const size_t MEL = (size_t)1024 * 1024;
    char* base = (char*)d_ws;

    short* Wqt = (short*)(base + 0 * 2 * MB);
    short* Wkt = (short*)(base + 1 * 2 * MB);
    short* Wvt = (short*)(base + 2 * 2 * MB);
    short* Wot = (short*)(base + 3 * 2 * MB);

    // tiers: weights 8MB [+ bits 1MB] + 4 bufs * z * 2MB
    int zdim;
    bool use_bits;
    if      (ws_size >= 74 * MB) { zdim = 8; use_bits = true; }
    else if (ws_size >= 42 * MB) { zdim = 4; use_bits = true; }
    else if (ws_size >= 26 * MB) { zdim = 2; use_bits = true; }
    else if (ws_size >= 18 * MB) { zdim = 1; use_bits = true; }
    else                         { zdim = 1; use_bits = false; }

    unsigned short* bits = (unsigned short*)(base + 8 * MB);
    char* bufs = base + (use_bits ? 9 : 8) * MB;
    const size_t bufB = (size_t)zdim * 2 * MB;
    short* Qw  = (short*)(bufs);
    short* Kw  = (short*)(bufs + bufB);
    short* Vw  = (short*)(bufs + 2 * bufB);
    short* ctx = (short*)(bufs + 3 * bufB);

    transpose_cast<<<dim3(32, 32), 256, 0, stream>>>(Wq, Wqt);
    transpose_cast<<<dim3(32, 32), 256, 0, stream>>>(Wk, Wkt);
    transpose_cast<<<dim3(32, 32), 256, 0, stream>>>(Wv, Wvt);
    transpose_cast<<<dim3(32, 32), 256, 0, stream>>>(Wo, Wot);
    if (use_bits)
        pack_mask<<<(BSZ * SEQL * SEQL) / 256, 256, 0, stream>>>(mask, bits);

    const int iters = BSZ / zdim;
    for (int it = 0; it < iters; ++it) {
        const size_t boff = (size_t)it * zdim * MEL;
        const float* qb = q + boff;
        const float* kb = k + boff;
        const float* vb = v + boff;
        float* ob = out + boff;
        const void* mb = use_bits
            ? (const void*)(bits + (size_t)it * zdim * SEQL * 64)
            : (const void*)(mask + (size_t)it * zdim * SEQL * SEQL);

        const int castGrid = zdim * 512;  // zdim*1M elems / 8 per thread / 256
        // ctx is dead until attn writes it: reuse as bf16 A-scratch.
        cast_bf16<<<castGrid, 256, 0, stream>>>(qb, ctx);
        gemm_mfma<0><<<dim3(8, 8, zdim), 256, 0, stream>>>(ctx, Wqt, bq, Qw);
        cast_bf16<<<castGrid, 256, 0, stream>>>(kb, ctx);
        gemm_mfma<0><<<dim3(8, 8, zdim), 256, 0, stream>>>(ctx, Wkt, bk, Kw);
        cast_bf16<<<castGrid, 256, 0, stream>>>(vb, ctx);
        gemm_mfma<2><<<dim3(8, 8, zdim), 256, 0, stream>>>(ctx, Wvt, bv, Vw);

        const int attnBlocks = 16 * 16 * zdim;  // 1D, XCD-swizzled in-kernel
        if (use_bits)
            attn_mfma<true><<<attnBlocks, 256, 0, stream>>>(Qw, Kw, Vw, mb, ctx);
        else
            attn_mfma<false><<<attnBlocks, 256, 0, stream>>>(Qw, Kw, Vw, mb, ctx);

        gemm_mfma<1><<<dim3(8, 8, zdim), 256, 0, stream>>>(ctx, Wot, bo, ob);
    }
}